// Round 1
// baseline (738.568 us; speedup 1.0000x reference)
//
#include <hip/hip_runtime.h>

#define TOPN 1000
#define NMS_TH 0.7

// ---------------------------------------------------------------------------
// Kernel A: per-box corners (CCW, double) + areas
// ---------------------------------------------------------------------------
__global__ void corners_kernel(const float* __restrict__ boxes,
                               double* __restrict__ cor,   // N*8: x0,y0,x1,y1,x2,y2,x3,y3
                               double* __restrict__ areas, // N
                               int N) {
    int i = blockIdx.x * blockDim.x + threadIdx.x;
    if (i >= N) return;
    double xc = boxes[i * 5 + 0];
    double yc = boxes[i * 5 + 1];
    double w  = boxes[i * 5 + 2];
    double h  = boxes[i * 5 + 3];
    double t  = boxes[i * 5 + 4];
    double th = t * 0.017453292519943295;  // pi/180
    double c = cos(th), s = sin(th);
    const double lx[4] = {0.5, -0.5, -0.5, 0.5};
    const double ly[4] = {0.5, 0.5, -0.5, -0.5};
#pragma unroll
    for (int k = 0; k < 4; ++k) {
        double x = xc + lx[k] * w * c - ly[k] * h * s;
        double y = yc + lx[k] * w * s + ly[k] * h * c;
        cor[i * 8 + k * 2 + 0] = x;
        cor[i * 8 + k * 2 + 1] = y;
    }
    areas[i] = w * h;
}

// ---------------------------------------------------------------------------
// Exact convex-quad intersection area via Green's theorem:
// sum over edges of P of cross(a,b) where [a,b] is the edge segment clipped
// to the interior of Q (t-interval from 4 half-plane constraints).
// Fully static — no dynamic polygon arrays.
// ---------------------------------------------------------------------------
__device__ __forceinline__ double clip_sum(const double* __restrict__ px,
                                           const double* __restrict__ py,
                                           const double* __restrict__ qx,
                                           const double* __restrict__ qy) {
    double acc = 0.0;
#pragma unroll
    for (int e = 0; e < 4; ++e) {
        double x0 = px[e], y0 = py[e];
        double x1 = px[(e + 1) & 3], y1 = py[(e + 1) & 3];
        double dx = x1 - x0, dy = y1 - y0;
        double t0 = 0.0, t1 = 1.0;
        bool empty = false;
#pragma unroll
        for (int f = 0; f < 4; ++f) {
            double ex0 = qx[f], ey0 = qy[f];
            double ex1 = qx[(f + 1) & 3], ey1 = qy[(f + 1) & 3];
            double edx = ex1 - ex0, edy = ey1 - ey0;
            // signed distance (scaled): >=0 means inside (left of CCW edge)
            double f0 = edx * (y0 - ey0) - edy * (x0 - ex0);
            double f1 = edx * (y1 - ey0) - edy * (x1 - ex0);
            double df = f1 - f0;
            if (df > 0.0) {
                double tt = -f0 / df;
                t0 = fmax(t0, tt);
            } else if (df < 0.0) {
                double tt = -f0 / df;
                t1 = fmin(t1, tt);
            } else if (f0 < 0.0) {
                empty = true;
            }
        }
        if (!empty && t0 < t1) {
            double ax = x0 + t0 * dx, ay = y0 + t0 * dy;
            double bx = x0 + t1 * dx, by = y0 + t1 * dy;
            acc += ax * by - bx * ay;
        }
    }
    return acc;
}

// ---------------------------------------------------------------------------
// Kernel B: suppression bitmask.  Grid (WORDS, N); block = 64 (one wave).
// Wave handles row i = blockIdx.y, columns j = blockIdx.x*64 + lane.
// Bit set iff (j > i) && iou(i,j) > 0.7.  __ballot forms the 64-bit word.
// ---------------------------------------------------------------------------
__global__ __launch_bounds__(64) void iou_bits_kernel(
    const double* __restrict__ cor, const double* __restrict__ areas,
    unsigned long long* __restrict__ mask, int N, int words) {
    int i = blockIdx.y;
    int j = blockIdx.x * 64 + (int)threadIdx.x;
    bool bit = false;
    if (j < N && j > i) {
        double px[4], py[4], qx[4], qy[4];
#pragma unroll
        for (int k = 0; k < 4; ++k) {
            px[k] = cor[i * 8 + k * 2 + 0];
            py[k] = cor[i * 8 + k * 2 + 1];
            qx[k] = cor[j * 8 + k * 2 + 0];
            qy[k] = cor[j * 8 + k * 2 + 1];
        }
        double inter = 0.5 * (clip_sum(px, py, qx, qy) + clip_sum(qx, qy, px, py));
        inter = fmax(inter, 0.0);
        double uni = areas[i] + areas[j] - inter;
        double iou = inter / fmax(uni, 1e-8);
        bit = iou > NMS_TH;
    }
    unsigned long long w = __ballot(bit);
    if (threadIdx.x == 0) mask[(size_t)i * words + blockIdx.x] = w;
}

// ---------------------------------------------------------------------------
// Kernel C: sequential greedy sweep + index emission.  One block of 64
// threads (one wave).  Lanes 0..words-1 hold the 'removed' bitmask words in
// registers; keep-bit broadcast via __shfl; mask row prefetched one ahead.
// ---------------------------------------------------------------------------
__global__ __launch_bounds__(64) void greedy_kernel(
    const unsigned long long* __restrict__ mask, int* __restrict__ out,
    int N, int words, int topn) {
    int lane = threadIdx.x;
    unsigned long long removed = 0ULL;
    unsigned long long nextrow = (lane < words) ? mask[lane] : 0ULL;  // row 0
    for (int i = 0; i < N; ++i) {
        unsigned long long row = nextrow;
        int inext = i + 1;
        nextrow = (inext < N && lane < words)
                      ? mask[(size_t)inext * words + lane]
                      : 0ULL;
        unsigned long long rw = __shfl(removed, i >> 6);
        bool kept = !((rw >> (i & 63)) & 1ULL);
        if (kept) removed |= row;  // row has bits only for j > i
    }

    // keep mask per lane-owned word, clipped to N bits
    unsigned long long keepw = 0ULL;
    if (lane < words) {
        keepw = ~removed;
        int base = lane * 64;
        int valid = N - base;
        if (valid <= 0)
            keepw = 0ULL;
        else if (valid < 64)
            keepw &= ((1ULL << valid) - 1ULL);
    }

    // exclusive prefix of popcounts across lanes
    int pc = __popcll(keepw);
    int scan = pc;
#pragma unroll
    for (int off = 1; off < 64; off <<= 1) {
        int v = __shfl_up(scan, off);
        if (lane >= off) scan += v;
    }
    int base_out = scan - pc;
    int total = __shfl(scan, words - 1);

    // emit kept indices
    if (lane < words) {
        int pos = base_out;
        unsigned long long w = keepw;
        while (w) {
            int b = __ffsll(w) - 1;
            w &= w - 1ULL;
            if (pos < topn) out[pos] = lane * 64 + b;
            ++pos;
        }
    }
    // pad tail with -1
    for (int k = (total < topn ? total : topn) + lane; k < topn; k += 64)
        out[k] = -1;
}

// ---------------------------------------------------------------------------
extern "C" void kernel_launch(void* const* d_in, const int* in_sizes, int n_in,
                              void* d_out, int out_size, void* d_ws,
                              size_t ws_size, hipStream_t stream) {
    const float* boxes = (const float*)d_in[0];
    int N = in_sizes[0] / 5;          // 2000
    int words = (N + 63) / 64;        // 32
    int topn = out_size;              // 1000

    // workspace layout (all 8B-aligned)
    char* ws = (char*)d_ws;
    double* cor = (double*)ws;                          // N*8 doubles
    double* areas = (double*)(ws + (size_t)N * 8 * 8);  // N doubles
    unsigned long long* mask =
        (unsigned long long*)(ws + (size_t)N * 8 * 8 + (size_t)N * 8);

    corners_kernel<<<(N + 255) / 256, 256, 0, stream>>>(boxes, cor, areas, N);
    iou_bits_kernel<<<dim3(words, N), 64, 0, stream>>>(cor, areas, mask, N,
                                                       words);
    greedy_kernel<<<1, 64, 0, stream>>>(mask, (int*)d_out, N, words, topn);
}

// Round 2
// 317.394 us; speedup vs baseline: 2.3270x; 2.3270x over previous
//
#include <hip/hip_runtime.h>

#define TOPN 1000
#define NMS_TH 0.7

// ---------------------------------------------------------------------------
// Kernel A: per-box corners (CCW, double) + areas
// ---------------------------------------------------------------------------
__global__ void corners_kernel(const float* __restrict__ boxes,
                               double* __restrict__ cor,   // N*8: x0,y0,x1,y1,x2,y2,x3,y3
                               double* __restrict__ areas, // N
                               int N) {
    int i = blockIdx.x * blockDim.x + threadIdx.x;
    if (i >= N) return;
    double xc = boxes[i * 5 + 0];
    double yc = boxes[i * 5 + 1];
    double w  = boxes[i * 5 + 2];
    double h  = boxes[i * 5 + 3];
    double t  = boxes[i * 5 + 4];
    double th = t * 0.017453292519943295;  // pi/180
    double c = cos(th), s = sin(th);
    const double lx[4] = {0.5, -0.5, -0.5, 0.5};
    const double ly[4] = {0.5, 0.5, -0.5, -0.5};
#pragma unroll
    for (int k = 0; k < 4; ++k) {
        double x = xc + lx[k] * w * c - ly[k] * h * s;
        double y = yc + lx[k] * w * s + ly[k] * h * c;
        cor[i * 8 + k * 2 + 0] = x;
        cor[i * 8 + k * 2 + 1] = y;
    }
    areas[i] = w * h;
}

// ---------------------------------------------------------------------------
// Exact convex-quad intersection area via Green's theorem: sum over edges of
// P of cross(a,b) with [a,b] the edge clipped to Q's interior (t-interval
// from 4 half-plane constraints). Fully static — no dynamic polygon arrays.
// ---------------------------------------------------------------------------
__device__ __forceinline__ double clip_sum(const double* __restrict__ px,
                                           const double* __restrict__ py,
                                           const double* __restrict__ qx,
                                           const double* __restrict__ qy) {
    double acc = 0.0;
#pragma unroll
    for (int e = 0; e < 4; ++e) {
        double x0 = px[e], y0 = py[e];
        double x1 = px[(e + 1) & 3], y1 = py[(e + 1) & 3];
        double dx = x1 - x0, dy = y1 - y0;
        double t0 = 0.0, t1 = 1.0;
        bool empty = false;
#pragma unroll
        for (int f = 0; f < 4; ++f) {
            double ex0 = qx[f], ey0 = qy[f];
            double ex1 = qx[(f + 1) & 3], ey1 = qy[(f + 1) & 3];
            double edx = ex1 - ex0, edy = ey1 - ey0;
            double f0 = edx * (y0 - ey0) - edy * (x0 - ex0);
            double f1 = edx * (y1 - ey0) - edy * (x1 - ex0);
            double df = f1 - f0;
            if (df > 0.0) {
                t0 = fmax(t0, -f0 / df);
            } else if (df < 0.0) {
                t1 = fmin(t1, -f0 / df);
            } else if (f0 < 0.0) {
                empty = true;
            }
        }
        if (!empty && t0 < t1) {
            double ax = x0 + t0 * dx, ay = y0 + t0 * dy;
            double bx = x0 + t1 * dx, by = y0 + t1 * dy;
            acc += ax * by - bx * ay;
        }
    }
    return acc;
}

// ---------------------------------------------------------------------------
// Kernel B: suppression bitmask.  Grid (WORDS, N); block = 64 (one wave).
// Bit set iff (j > i) && iou(i,j) > 0.7.  __ballot forms the 64-bit word.
// ---------------------------------------------------------------------------
__global__ __launch_bounds__(64) void iou_bits_kernel(
    const double* __restrict__ cor, const double* __restrict__ areas,
    unsigned long long* __restrict__ mask, int N, int words) {
    int i = blockIdx.y;
    int j = blockIdx.x * 64 + (int)threadIdx.x;
    bool bit = false;
    if (j < N && j > i) {
        double px[4], py[4], qx[4], qy[4];
#pragma unroll
        for (int k = 0; k < 4; ++k) {
            px[k] = cor[i * 8 + k * 2 + 0];
            py[k] = cor[i * 8 + k * 2 + 1];
            qx[k] = cor[j * 8 + k * 2 + 0];
            qy[k] = cor[j * 8 + k * 2 + 1];
        }
        double inter = 0.5 * (clip_sum(px, py, qx, qy) + clip_sum(qx, qy, px, py));
        inter = fmax(inter, 0.0);
        double uni = areas[i] + areas[j] - inter;
        double iou = inter / fmax(uni, 1e-8);
        bit = iou > NMS_TH;
    }
    unsigned long long w = __ballot(bit);
    if (threadIdx.x == 0) mask[(size_t)i * words + blockIdx.x] = w;
}

// ---------------------------------------------------------------------------
// Kernel C: chunked greedy sweep.  One wave.  Lane L owns 'removed' word L.
// Per 64-box chunk c: all lanes load the chunk's 64 row-words (lane L gets
// column-word L of each row); lane c resolves the intra-chunk recurrence
// with register-only dependent ops (word c == intra-chunk columns); one
// __shfl broadcasts the kept-word; all lanes apply kept rows in parallel.
// Serial critical path: words × 64 reg-ALU steps instead of N global-latency
// round-trips.
// ---------------------------------------------------------------------------
__global__ __launch_bounds__(64, 1) void greedy_kernel(
    const unsigned long long* __restrict__ mask, int* __restrict__ out,
    int N, int words, int topn) {
    int lane = threadIdx.x;
    unsigned long long removed = 0ULL;

    for (int c = 0; c < words; ++c) {
        int base = c * 64;
        int cnt = N - base;  // may exceed 64; clip below
        // Stage the chunk's rows: rows[i] = word 'lane' of row (base+i).
        unsigned long long rows[64];
#pragma unroll
        for (int i = 0; i < 64; ++i) {
            rows[i] = (i < cnt && lane < words)
                          ? mask[(size_t)(base + i) * words + lane]
                          : 0ULL;
        }
        // Intra-chunk sequential resolve on lane c (register-only chain).
        unsigned long long K = 0ULL;
        if (lane == c) {
            unsigned long long rem = removed;
#pragma unroll
            for (int i = 0; i < 64; ++i) {
                if (!((rem >> i) & 1ULL)) {
                    K |= 1ULL << i;
                    rem |= rows[i];
                }
            }
            removed = rem;
        }
        K = __shfl(K, c);
        // Parallel apply of kept rows to all lanes' words (idempotent).
#pragma unroll
        for (int i = 0; i < 64; ++i) {
            unsigned long long sel = 0ULL - (unsigned long long)((K >> i) & 1ULL);
            removed |= rows[i] & sel;
        }
    }

    // keep mask per lane-owned word, clipped to N bits
    unsigned long long keepw = 0ULL;
    if (lane < words) {
        keepw = ~removed;
        int base = lane * 64;
        int valid = N - base;
        if (valid <= 0)
            keepw = 0ULL;
        else if (valid < 64)
            keepw &= ((1ULL << valid) - 1ULL);
    }

    // exclusive prefix of popcounts across lanes
    int pc = __popcll(keepw);
    int scan = pc;
#pragma unroll
    for (int off = 1; off < 64; off <<= 1) {
        int v = __shfl_up(scan, off);
        if (lane >= off) scan += v;
    }
    int base_out = scan - pc;
    int total = __shfl(scan, words - 1);

    // emit kept indices
    if (lane < words) {
        int pos = base_out;
        unsigned long long w = keepw;
        while (w) {
            int b = __ffsll(w) - 1;
            w &= w - 1ULL;
            if (pos < topn) out[pos] = lane * 64 + b;
            ++pos;
        }
    }
    // pad tail with -1
    for (int k = (total < topn ? total : topn) + lane; k < topn; k += 64)
        out[k] = -1;
}

// ---------------------------------------------------------------------------
extern "C" void kernel_launch(void* const* d_in, const int* in_sizes, int n_in,
                              void* d_out, int out_size, void* d_ws,
                              size_t ws_size, hipStream_t stream) {
    const float* boxes = (const float*)d_in[0];
    int N = in_sizes[0] / 5;          // 2000
    int words = (N + 63) / 64;        // 32
    int topn = out_size;              // 1000

    char* ws = (char*)d_ws;
    double* cor = (double*)ws;                          // N*8 doubles
    double* areas = (double*)(ws + (size_t)N * 8 * 8);  // N doubles
    unsigned long long* mask =
        (unsigned long long*)(ws + (size_t)N * 8 * 8 + (size_t)N * 8);

    corners_kernel<<<(N + 255) / 256, 256, 0, stream>>>(boxes, cor, areas, N);
    iou_bits_kernel<<<dim3(words, N), 64, 0, stream>>>(cor, areas, mask, N,
                                                       words);
    greedy_kernel<<<1, 64, 0, stream>>>(mask, (int*)d_out, N, words, topn);
}